// Round 1
// 1706.434 us; speedup vs baseline: 1.7212x; 1.7212x over previous
//
#include <hip/hip_runtime.h>
#include <hip/hip_bf16.h>

#define B_ 8
#define C_ 1024
#define T_ 4096
#define K_ 1024
#define D_ 8
#define NOUTLL ((size_t)33554432)   // B*C*T

// ---------------- workspace byte offsets ----------------
#define OFF_FLAG   0
#define OFF_WTD    256                         // 65536 doubles [c][r], r = s*8+d
#define OFF_P4D    (OFF_WTD  + 65536u*8u)      // 2*8*64*4096 doubles (c-chunk partial projections)
#define OFF_MD     (OFF_P4D  + 4194304u*8u)    // 27*64 doubles (26 cross matrices + zero block)
#define OFF_BPD    (OFF_MD   + 1728u*8u)       // 64 doubles effective bias
#define OFF_CBND   (OFF_BPD  + 64u*8u)         // 65536 doubles normalized codebooks (f64)
#define OFF_ACCD   (OFF_CBND + 65536u*8u)      // loss accumulator (double)
#define OFF_CBNF   (OFF_ACCD + 256u)           // 65536 floats normalized codebooks (f32)
#define OFF_CBF    (OFF_CBNF + 65536u*4u)      // 65536 floats raw codebooks
#define OFF_OWT    (OFF_CBF  + 65536u*4u)      // 65536 floats out_w transposed [c][r]
#define OFF_OBT    (OFF_OWT  + 65536u*4u)      // 8192 floats out_b transposed [c][s]
#define OFF_MASK   (OFF_OBT  + 8192u*4u)       // 8 floats res_mask
#define OFF_CODES  (OFF_MASK + 256u)           // 8*64*4096 floats chosen codes [b][r][t]

__device__ __forceinline__ float loadf(const void* p, int i, bool bf){
  if (bf){
    unsigned short u = ((const unsigned short*)p)[i];
    return __uint_as_float(((unsigned int)u) << 16);
  }
  return ((const float*)p)[i];
}

__device__ __forceinline__ const void* stage_ptr(const void* p, const void* c,
                                                 const void* t, const void* r,
                                                 int s, int& sub){
  if (s == 0){ sub = 0; return p; }
  if (s <= 2){ sub = s - 1; return c; }
  if (s <= 4){ sub = s - 3; return t; }
  sub = s - 5; return r;
}

// ---------------- detect input dtype (bf16 vs f32) ----------------
__global__ void detect_k(const unsigned int* __restrict__ x, float* __restrict__ flag){
  if (blockIdx.x == 0 && threadIdx.x == 0){
    int cnt = 0;
    for (int i = 0; i < 256; ++i){
      unsigned int e = (x[i] >> 23) & 0xFFu;
      if (e >= 90u && e <= 150u) ++cnt;   // plausible f32 N(0,1) exponent
    }
    *flag = (cnt >= 200) ? 0.0f : 1.0f;   // 0 = f32, 1 = bf16
  }
}

// ---------------- convert / transpose weights ----------------
__global__ __launch_bounds__(256) void convert_k(
    const void* __restrict__ piw, const void* __restrict__ ciw, const void* __restrict__ tiw, const void* __restrict__ riw,
    const void* __restrict__ pcb, const void* __restrict__ ccb, const void* __restrict__ tcb, const void* __restrict__ rcb,
    const void* __restrict__ pow_, const void* __restrict__ cow, const void* __restrict__ tow, const void* __restrict__ row_,
    const void* __restrict__ pob, const void* __restrict__ cob, const void* __restrict__ tob, const void* __restrict__ rob,
    const void* __restrict__ nap, const void* __restrict__ rnp, const void* __restrict__ rrp,
    const float* __restrict__ flag, double* __restrict__ Wt, double* __restrict__ cbn_d,
    float* __restrict__ cbn_f, float* __restrict__ cb_f, float* __restrict__ owT,
    float* __restrict__ obT, float* __restrict__ maskp){
  const bool bf = (*flag != 0.0f);
  const int blk = blockIdx.x, tid = threadIdx.x;
  if (blk < 256){
    int g = (blk << 8) + tid;
    int c = g >> 6, r = g & 63, s = r >> 3, d = r & 7;
    int sub; const void* p = stage_ptr(piw, ciw, tiw, riw, s, sub);
    Wt[g] = (double)loadf(p, ((sub << 3) + d) * 1024 + c, bf);
  } else if (blk < 288){
    int g = ((blk - 256) << 8) + tid;
    int s = g >> 10, k = g & 1023;
    int sub; const void* p = stage_ptr(pcb, ccb, tcb, rcb, s, sub);
    float v[8]; double n2 = 0.0;
    #pragma unroll
    for (int d = 0; d < 8; d++){
      v[d] = loadf(p, (((sub << 10) + k) << 3) + d, bf);
      n2 += (double)v[d] * (double)v[d];
    }
    double n = sqrt(n2); if (n < 1e-12) n = 1e-12;
    #pragma unroll
    for (int d = 0; d < 8; d++){
      double cn = (double)v[d] / n;
      cbn_d[((size_t)s << 13) + (k << 3) + d] = cn;
      cbn_f[(s << 13) + (k << 3) + d] = (float)cn;
      cb_f [(s << 13) + (k << 3) + d] = v[d];
    }
  } else if (blk < 544){
    int g = ((blk - 288) << 8) + tid;
    int c = g >> 6, s = (g >> 3) & 7, d = g & 7;
    int sub; const void* p = stage_ptr(pow_, cow, tow, row_, s, sub);
    owT[g] = loadf(p, (((sub << 10) + c) << 3) + d, bf);
  } else if (blk < 576){
    int g = ((blk - 544) << 8) + tid;
    int c = g >> 3, s = g & 7;
    int sub; const void* p = stage_ptr(pob, cob, tob, rob, s, sub);
    obT[g] = loadf(p, (sub << 10) + c, bf);
  } else {
    if (tid == 0){
      const unsigned int* na = (const unsigned int*)nap;
      const unsigned int* rn = (const unsigned int*)rnp;
      bool bytes_mode = (((na[0] | na[1] | rn[0] | rn[1]) & 0xFFFFFF00u) != 0u);
      for (int bb = 0; bb < 8; ++bb){
        int nav, rnv;
        if (bytes_mode){ nav = ((const unsigned char*)nap)[bb]; rnv = ((const unsigned char*)rnp)[bb]; }
        else           { nav = ((const int*)nap)[bb];           rnv = ((const int*)rnp)[bb]; }
        float rrv = loadf(rrp, bb, bf);
        maskp[bb] = nav ? (rnv ? 1.0f : 0.0f) : rrv;
      }
    }
  }
}

// ---------------- 8x8 cross matrices M[f][s] = in_w_f @ out_w_s, bias, acc zero ----------------
__global__ void setupM_k(const double* __restrict__ Wt, const float* __restrict__ owT,
                         const float* __restrict__ obT,
                         const void* __restrict__ pib, const void* __restrict__ cib,
                         const void* __restrict__ tib, const void* __restrict__ rib,
                         double* __restrict__ Md, double* __restrict__ bpd,
                         double* __restrict__ accd, const float* __restrict__ flag){
  const bool bf = (*flag != 0.0f);
  const int p = blockIdx.x, tid = threadIdx.x;
  if (p < 26){
    const int ftab[26] = {2,3,3,3,4,4,4,4,5,5,5,5,5,6,6,6,6,6,6,7,7,7,7,7,7,7};
    const int stab[26] = {1,0,1,2,0,1,2,3,0,1,2,3,4,0,1,2,3,4,5,0,1,2,3,4,5,6};
    int f = ftab[p], s = stab[p];
    int d = tid >> 3, i = tid & 7;
    double m = 0.0;
    for (int c = 0; c < 1024; ++c)
      m += Wt[(c << 6) + (f << 3) + d] * (double)owT[(c << 6) + (s << 3) + i];
    Md[(p << 6) + tid] = m;
  } else {
    Md[(26 << 6) + tid] = 0.0;          // zero block for non-dependency pairs
    if (tid == 0) *accd = 0.0;
    int f = tid >> 3, d = tid & 7;
    int sub; const void* ibp = stage_ptr(pib, cib, tib, rib, f, sub);
    double v = (double)loadf(ibp, (sub << 3) + d, bf);
    for (int s = 0; s < f; ++s){
      bool dep = (f >= 3) || (f == 2 && s == 1);
      if (!dep) continue;
      double acc = 0.0;
      for (int c = 0; c < 1024; ++c)
        acc += Wt[(c << 6) + (f << 3) + d] * (double)obT[(c << 3) + s];
      v -= acc;
    }
    bpd[tid] = v;
  }
}

// ---------------- Phase A: P[b][r][t] partial = in_w_stacked @ x (f64) ----------------
template<bool BF>
__device__ __forceinline__ void phaseA_body(const void* __restrict__ x, const double* __restrict__ Wt,
                                            double* __restrict__ P4, int b, int t, int ch){
  double acc[64];
  #pragma unroll
  for (int r = 0; r < 64; r++) acc[r] = 0.0;
  const int c0 = ch << 9;
  const size_t xb = ((size_t)b * C_ + c0) * T_ + t;
  for (int cc = 0; cc < 512; ++cc){
    float xv;
    if (BF){
      unsigned short u = ((const unsigned short*)x)[xb + (size_t)cc * T_];
      xv = __uint_as_float(((unsigned int)u) << 16);
    } else {
      xv = ((const float*)x)[xb + (size_t)cc * T_];
    }
    double xd = (double)xv;
    const double* w = Wt + ((size_t)(c0 + cc) << 6);
    #pragma unroll
    for (int r = 0; r < 64; r++) acc[r] = fma(w[r], xd, acc[r]);
  }
  double* o = P4 + ((size_t)(ch * 8 + b) * 64) * T_ + t;
  #pragma unroll
  for (int r = 0; r < 64; r++) o[(size_t)r * T_] = acc[r];
}

__global__ __launch_bounds__(256) void phaseA_k(const void* __restrict__ x, const double* __restrict__ Wt,
                                                double* __restrict__ P4, const float* __restrict__ flag){
  const int t = (blockIdx.x << 8) + threadIdx.x;
  const int b = blockIdx.y, ch = blockIdx.z;
  if (*flag != 0.0f) phaseA_body<true >(x, Wt, P4, b, t, ch);
  else               phaseA_body<false>(x, Wt, P4, b, t, ch);
}

// ---------------- Phase B: sequential 8-stage argmax chain (8 lanes per position) ----------------
__global__ __launch_bounds__(256) void phaseB_k(const double* __restrict__ P4, const double* __restrict__ Mp,
    const double* __restrict__ bp, const double* __restrict__ cbn_d, const float* __restrict__ cbn_f,
    const float* __restrict__ cb_f, float* __restrict__ codes, double* __restrict__ accd){
  __shared__ __align__(16) float  cbL[8224];     // swizzled f32 normalized codebook (one stage)
  __shared__ double proj[64 * 33];               // f64 projections, stride 33 vs pos
  __shared__ double Ml[27 * 64];                 // cross matrices
  __shared__ double red[4];
  const int tid = threadIdx.x;
  const int b  = blockIdx.y;
  const int t0 = blockIdx.x << 5;
  const int pos = tid >> 3, l = tid & 7;
  const int t = t0 + pos;

  for (int i = tid; i < 27 * 64; i += 256) Ml[i] = Mp[i];
  for (int i = tid; i < 2048; i += 256){
    int r = i >> 5, pp = i & 31;
    double v = bp[r];
    v += P4[((size_t)(0 * 8 + b) * 64 + r) * T_ + t0 + pp];
    v += P4[((size_t)(1 * 8 + b) * 64 + r) * T_ + t0 + pp];
    proj[r * 33 + pp] = v;
  }

  double loss = 0.0;
  for (int s = 0; s < 8; ++s){
    __syncthreads();
    for (int i = tid; i < 8192; i += 256)
      cbL[i + ((i >> 10) << 2)] = cbn_f[(s << 13) + i];
    __syncthreads();

    double zed[8]; float ze[8];
    #pragma unroll
    for (int d = 0; d < 8; d++){
      zed[d] = proj[((s << 3) + d) * 33 + pos];
      ze[d] = (float)zed[d];
    }

    // f32 scan of 128 codes/lane with top-2 tracking
    float b1 = -3.4e38f, b2 = -3.4e38f; int i1 = 0;
    const float4* cb4 = (const float4*)cbL;
    const int kb = l << 7;
    for (int j = 0; j < 128; ++j){
      int k = kb + j;
      float4 ca = cb4[(k << 1) + l];
      float4 cc = cb4[(k << 1) + l + 1];
      float d0 = ca.x*ze[0] + ca.y*ze[1] + ca.z*ze[2] + ca.w*ze[3]
               + cc.x*ze[4] + cc.y*ze[5] + cc.z*ze[6] + cc.w*ze[7];
      if (d0 > b1){ b2 = b1; b1 = d0; i1 = k; }
      else if (d0 > b2){ b2 = d0; }
    }
    // reduce top-2 across the 8 lanes of this position
    #pragma unroll
    for (int off = 1; off < 8; off <<= 1){
      float o1 = __shfl_xor(b1, off); int oi = __shfl_xor(i1, off);
      float o2 = __shfl_xor(b2, off);
      float lo = fminf(b1, o1);
      if (o1 > b1 || (o1 == b1 && oi < i1)){ b1 = o1; i1 = oi; }
      b2 = fmaxf(fmaxf(b2, o2), lo);
    }
    int bidx = i1;
    if (b1 - b2 < 1e-3f){
      // near-tie: exact f64 rescan
      double db = -1e300; int di = 1 << 20;
      const double* cbs = cbn_d + ((size_t)s << 13);
      for (int j = 0; j < 128; ++j){
        int k = kb + j;
        const double* rw = cbs + ((size_t)k << 3);
        double dd = rw[0]*zed[0] + rw[1]*zed[1] + rw[2]*zed[2] + rw[3]*zed[3]
                  + rw[4]*zed[4] + rw[5]*zed[5] + rw[6]*zed[6] + rw[7]*zed[7];
        if (dd > db){ db = dd; di = k; }
      }
      #pragma unroll
      for (int off = 1; off < 8; off <<= 1){
        double ov = __shfl_xor(db, off); int oi = __shfl_xor(di, off);
        if (ov > db || (ov == db && oi < di)){ db = ov; di = oi; }
      }
      bidx = di;
    }

    float code[8];
    const float* crow = cb_f + (s << 13) + (bidx << 3);
    #pragma unroll
    for (int d = 0; d < 8; d++) code[d] = crow[d];

    if (l == 0){
      double e = 0.0;
      #pragma unroll
      for (int d = 0; d < 8; d++){ double df = zed[d] - (double)code[d]; e += df * df; }
      loss += e;
    }
    codes[((size_t)((b << 6) + (s << 3) + l)) * T_ + t] = code[l];

    // corrections: lane l updates future stage f = l with M[f][s] @ code
    int moff = 26;
    if (l >= 3 && s < l) moff = ((l * l - l - 4) >> 1) + s;
    else if (l == 2 && s == 1) moff = 0;
    const double* M = Ml + (moff << 6);
    #pragma unroll
    for (int d = 0; d < 8; d++){
      double corr = 0.0;
      #pragma unroll
      for (int i2 = 0; i2 < 8; i2++) corr += M[(d << 3) + i2] * (double)code[i2];
      proj[((l << 3) + d) * 33 + pos] -= corr;
    }
  }

  #pragma unroll
  for (int off = 1; off < 64; off <<= 1) loss += __shfl_xor(loss, off);
  if ((tid & 63) == 0) red[tid >> 6] = loss;
  __syncthreads();
  if (tid == 0) atomicAdd(accd, red[0] + red[1] + red[2] + red[3]);
}

// ---------------- Phase C: out_w @ codes, write 5 output tensors ----------------
// Re-parallelized: grid (T/256, C/64, B), 256 threads. Each thread: one t,
// 64-row c chunk. Codes held in registers; identical per-element arithmetic
// (same summation order) as before, so output is bit-identical. Non-temporal
// stores: outputs are write-once streams, keep L2 for codes/owT.
template<bool BFOUT>
__device__ __forceinline__ void phaseC_body(const float* __restrict__ codes, const float* __restrict__ owT,
    const float* __restrict__ obT, const float* __restrict__ maskp, void* __restrict__ dout,
    int b, int t, int c0){
  float cr[64];
  #pragma unroll
  for (int r = 0; r < 64; r++) cr[r] = codes[((size_t)((b << 6) + r)) * T_ + t];
  const float mask = maskp[b];
  const size_t base0 = (size_t)b * C_ * T_ + t;
  float* of = (float*)dout;
  __hip_bfloat16* o16 = (__hip_bfloat16*)dout;
  for (int c = c0; c < c0 + 64; ++c){
    const float* w = owT + (c << 6);
    const float* ob = obT + (c << 3);
    float zp = ob[0];
    float zc = ob[1] + ob[2];
    float zt = ob[3] + ob[4];
    float zr = ob[5] + ob[6] + ob[7];
    #pragma unroll
    for (int i = 0;  i < 8;  i++) zp += w[i] * cr[i];
    #pragma unroll
    for (int i = 8;  i < 24; i++) zc += w[i] * cr[i];
    #pragma unroll
    for (int i = 24; i < 40; i++) zt += w[i] * cr[i];
    #pragma unroll
    for (int i = 40; i < 64; i++) zr += w[i] * cr[i];
    float outs = zp + zc + zt + mask * zr;
    size_t idx = base0 + (size_t)c * T_;
    if (BFOUT){
      __hip_bfloat16 v0 = __float2bfloat16(outs);
      __hip_bfloat16 v1 = __float2bfloat16(zp);
      __hip_bfloat16 v2 = __float2bfloat16(zc);
      __hip_bfloat16 v3 = __float2bfloat16(zt);
      __hip_bfloat16 v4 = __float2bfloat16(zr);
      __builtin_nontemporal_store(*(unsigned short*)&v0, (unsigned short*)(o16 + idx));
      __builtin_nontemporal_store(*(unsigned short*)&v1, (unsigned short*)(o16 + idx + NOUTLL));
      __builtin_nontemporal_store(*(unsigned short*)&v2, (unsigned short*)(o16 + idx + 2*NOUTLL));
      __builtin_nontemporal_store(*(unsigned short*)&v3, (unsigned short*)(o16 + idx + 3*NOUTLL));
      __builtin_nontemporal_store(*(unsigned short*)&v4, (unsigned short*)(o16 + idx + 4*NOUTLL));
    } else {
      __builtin_nontemporal_store(outs, of + idx);
      __builtin_nontemporal_store(zp,   of + idx + NOUTLL);
      __builtin_nontemporal_store(zc,   of + idx + 2*NOUTLL);
      __builtin_nontemporal_store(zt,   of + idx + 3*NOUTLL);
      __builtin_nontemporal_store(zr,   of + idx + 4*NOUTLL);
    }
  }
}

__global__ __launch_bounds__(256) void phaseC_k(const float* __restrict__ codes, const float* __restrict__ owT,
    const float* __restrict__ obT, const float* __restrict__ maskp, const float* __restrict__ flag,
    void* __restrict__ dout){
  const int t = (blockIdx.x << 8) + threadIdx.x;
  const int c0 = blockIdx.y << 6;
  const int b = blockIdx.z;
  if (*flag != 0.0f) phaseC_body<true >(codes, owT, obT, maskp, dout, b, t, c0);
  else               phaseC_body<false>(codes, owT, obT, maskp, dout, b, t, c0);
}

__global__ void fin_k(const double* __restrict__ accd, const float* __restrict__ flag, void* __restrict__ dout){
  if (threadIdx.x == 0 && blockIdx.x == 0){
    float commit = (float)(*accd * (1.0 / 262144.0));
    if (*flag != 0.0f){
      __hip_bfloat16* o = (__hip_bfloat16*)dout;
      o[5 * NOUTLL]     = __float2bfloat16(commit);
      o[5 * NOUTLL + 1] = __float2bfloat16(commit);
    } else {
      float* o = (float*)dout;
      o[5 * NOUTLL] = commit;
      o[5 * NOUTLL + 1] = commit;
    }
  }
}

extern "C" void kernel_launch(void* const* d_in, const int* in_sizes, int n_in,
                              void* d_out, int out_size, void* d_ws, size_t ws_size,
                              hipStream_t stream){
  (void)in_sizes; (void)n_in; (void)out_size; (void)ws_size;
  char* ws = (char*)d_ws;
  float*  FLAG  = (float*) (ws + OFF_FLAG);
  double* WTD   = (double*)(ws + OFF_WTD);
  double* P4D   = (double*)(ws + OFF_P4D);
  double* MD    = (double*)(ws + OFF_MD);
  double* BPD   = (double*)(ws + OFF_BPD);
  double* CBND  = (double*)(ws + OFF_CBND);
  double* ACCD  = (double*)(ws + OFF_ACCD);
  float*  CBNF  = (float*) (ws + OFF_CBNF);
  float*  CBF   = (float*) (ws + OFF_CBF);
  float*  OWT   = (float*) (ws + OFF_OWT);
  float*  OBT   = (float*) (ws + OFF_OBT);
  float*  MASK  = (float*) (ws + OFF_MASK);
  float*  CODES = (float*) (ws + OFF_CODES);

  detect_k<<<1, 64, 0, stream>>>((const unsigned int*)d_in[0], FLAG);
  convert_k<<<577, 256, 0, stream>>>(
      d_in[5],  d_in[10], d_in[15], d_in[20],   // in_w  p c t r
      d_in[7],  d_in[12], d_in[17], d_in[22],   // cb
      d_in[8],  d_in[13], d_in[18], d_in[23],   // out_w
      d_in[9],  d_in[14], d_in[19], d_in[24],   // out_b
      d_in[2],  d_in[3],  d_in[4],              // flags + res_rand
      FLAG, WTD, CBND, CBNF, CBF, OWT, OBT, MASK);
  setupM_k<<<27, 64, 0, stream>>>(WTD, OWT, OBT, d_in[6], d_in[11], d_in[16], d_in[21],
                                  MD, BPD, ACCD, FLAG);
  phaseA_k<<<dim3(16, 8, 2), 256, 0, stream>>>(d_in[0], WTD, P4D, FLAG);
  phaseB_k<<<dim3(128, 8), 256, 0, stream>>>(P4D, MD, BPD, CBND, CBNF, CBF, CODES, ACCD);
  phaseC_k<<<dim3(16, 16, 8), 256, 0, stream>>>(CODES, OWT, OBT, MASK, FLAG, d_out);
  fin_k<<<1, 64, 0, stream>>>(ACCD, FLAG, d_out);
}